// Round 1
// baseline (727.258 us; speedup 1.0000x reference)
//
#include <hip/hip_runtime.h>
#include <hip/hip_bf16.h>
#include <stdint.h>

typedef unsigned short u16;
typedef __attribute__((ext_vector_type(8))) short bf16x8;          // 8 bf16 in 4 VGPRs
typedef __attribute__((ext_vector_type(4))) short bf16x4;          // 4 bf16 in 2 VGPRs
typedef __attribute__((ext_vector_type(8))) unsigned short u16x8;  // 16B store unit
typedef __attribute__((ext_vector_type(4))) float f32x4;

#define NTOK 49
#define CDIM 256
#define NHEAD 8
#define HDIM 32
#define SCALE_F 0.17677669529663687f  /* 32^-0.5 */

static __device__ inline u16 f2b(float f) {
    union { float f; unsigned u; } v; v.f = f;
    unsigned r = v.u + 0x7fff + ((v.u >> 16) & 1);   // RNE
    return (u16)(r >> 16);
}

// async global->LDS, 16B per lane; dest = wave-uniform base + lane*16
#define GLOAD_LDS16(g, l) __builtin_amdgcn_global_load_lds( \
    (const __attribute__((address_space(1))) unsigned int*)(g), \
    (__attribute__((address_space(3))) unsigned int*)(l), 16, 0, 0)

// ---------------------------------------------------------------------------
// fp32 -> bf16 converter, 8 elements/thread
// ---------------------------------------------------------------------------
__global__ __launch_bounds__(256) void conv_bf16(
    const float* __restrict__ src, u16* __restrict__ dst, int n8)
{
    int i = blockIdx.x * 256 + threadIdx.x;
    if (i < n8) {
        float4 a = ((const float4*)src)[2 * i];
        float4 b = ((const float4*)src)[2 * i + 1];
        u16x8 v;
        v[0] = f2b(a.x); v[1] = f2b(a.y); v[2] = f2b(a.z); v[3] = f2b(a.w);
        v[4] = f2b(b.x); v[5] = f2b(b.y); v[6] = f2b(b.z); v[7] = f2b(b.w);
        ((u16x8*)dst)[i] = v;
    }
}

// ---------------------------------------------------------------------------
// comb[m][h][64][64] = bias_table[rel_index[i,j], h] + mask[m,i,j], fp32.
// Padding (i>=49 || j>=49) = -1e9 so softmax sees exp(..)=0.
// ---------------------------------------------------------------------------
__global__ __launch_bounds__(256) void build_comb(
    const float* __restrict__ bias_table,   // [169,8] fp32
    const float* __restrict__ mask,         // [64,49,49] fp32
    const int*   __restrict__ rel_index,    // [49,49] int32
    float* __restrict__ comb)               // [64,8,64,64]
{
    int idx = blockIdx.x * 256 + threadIdx.x;       // 2097152
    int j = idx & 63, i = (idx >> 6) & 63, h = (idx >> 12) & 7, m = idx >> 15;
    float v = -1e9f;
    if (i < NTOK && j < NTOK) {
        int rel = rel_index[i * NTOK + j];
        v = bias_table[rel * NHEAD + h] + mask[m * (NTOK * NTOK) + i * NTOK + j];
    }
    comb[idx] = v;
}

// ---------------------------------------------------------------------------
// QKV projection: C[rows,768] = A[rows,256] @ W^T + b  (bf16 in, fp32 acc,
// bf16 out). 128x128 tile, BK=64, 4 waves (2x2), each wave 64x64 via 4x4
// mfma_f32_16x16x32_bf16. Staging via global_load_lds (16B) into an
// XOR-swizzled unpadded LDS layout.  (unchanged this round)
// ---------------------------------------------------------------------------
__global__ __launch_bounds__(256) void qkv_gemm(
    const u16*  __restrict__ A,     // [rows,256] bf16
    const u16*  __restrict__ Wt,    // [768,256]  bf16
    const float* __restrict__ bias, // [768] fp32
    u16* __restrict__ Cout)         // [rows,768] bf16
{
    __shared__ u16 As[128 * 64];
    __shared__ u16 Bs[128 * 64];

    const int t = threadIdx.x;
    const int bm = blockIdx.x, bn = blockIdx.y;
    const int wave = t >> 6, lane = t & 63;
    const int wm = wave >> 1, wn = wave & 1;
    const int lrow = lane & 15, quad = lane >> 4;

    f32x4 acc[4][4];
#pragma unroll
    for (int i = 0; i < 4; i++)
#pragma unroll
        for (int j = 0; j < 4; j++) acc[i][j] = (f32x4){0.f, 0.f, 0.f, 0.f};

    const int dr = lane >> 3;                 // 0..7
    const int dc = ((lane & 7) ^ dr) * 8;     // swizzled col (elems)
    const u16* Ag = A  + (size_t)(bm * 128 + wave * 32) * CDIM;
    const u16* Bg = Wt + (size_t)(bn * 128 + wave * 32) * CDIM;

#pragma unroll
    for (int kt = 0; kt < 4; kt++) {
        if (kt) __syncthreads();
        const int k0 = kt * 64;
#pragma unroll
        for (int i = 0; i < 4; i++) {
            GLOAD_LDS16(Ag + (size_t)(i * 8 + dr) * CDIM + k0 + dc, &As[(wave * 32 + i * 8) * 64]);
            GLOAD_LDS16(Bg + (size_t)(i * 8 + dr) * CDIM + k0 + dc, &Bs[(wave * 32 + i * 8) * 64]);
        }
        __syncthreads();   // drains vmcnt (DMA) before LDS reads
#pragma unroll
        for (int kk = 0; kk < 2; kk++) {
            const int xr = kk * 4 + quad;                 // 16B chunk index of kb
            const int sw = ((xr ^ (lrow & 7)) << 3);      // swizzled elem offset
            bf16x8 af[4], bfr[4];
#pragma unroll
            for (int tm = 0; tm < 4; tm++)
                af[tm] = *(const bf16x8*)&As[(wm * 64 + tm * 16 + lrow) * 64 + sw];
#pragma unroll
            for (int tn = 0; tn < 4; tn++)
                bfr[tn] = *(const bf16x8*)&Bs[(wn * 64 + tn * 16 + lrow) * 64 + sw];
#pragma unroll
            for (int tm = 0; tm < 4; tm++)
#pragma unroll
                for (int tn = 0; tn < 4; tn++)
                    acc[tm][tn] = __builtin_amdgcn_mfma_f32_16x16x32_bf16(
                        af[tm], bfr[tn], acc[tm][tn], 0, 0, 0);
        }
    }

    // epilogue: +bias, bf16 store. C/D layout: col=lane&15, row=quad*4+reg.
#pragma unroll
    for (int tn = 0; tn < 4; tn++) {
        int gcol = bn * 128 + wn * 64 + tn * 16 + lrow;
        float bv = bias[gcol];
#pragma unroll
        for (int tm = 0; tm < 4; tm++) {
            int grow0 = bm * 128 + wm * 64 + tm * 16 + quad * 4;
#pragma unroll
            for (int r = 0; r < 4; r++)
                Cout[(size_t)(grow0 + r) * 768 + gcol] = f2b(acc[tm][tn][r] + bv);
        }
    }
}

// ---------------------------------------------------------------------------
// Window attention v3: 1-wave blocks; grid (64 masks, NHEAD * G/4).
// SWAPPED QK^T: s = mfma(K, Q) puts q on the lane axis, k on the quad/reg
// axis.  The resulting C-layout IS the B-operand layout of
// mfma_f32_16x16x16_bf16, so P feeds PV straight from registers after a
// bf16 pack -- no P LDS buffer, no shuffle transpose.  Softmax sum per q =
// 16 in-lane adds + 2 shfl_xor.  Normalization deferred to the epilogue
// (per-q sum is lane-local; e values bounded, bf16 has fp32 range).
// comb streamed transposed per window as float4 from L2/L3 (8 MB resident)
// instead of 64 pinned VGPRs.  K processed in two 32-token halves so score
// accumulators peak at 32 regs.  LDS = vT only (4.6 KB).
// ---------------------------------------------------------------------------
__global__ __launch_bounds__(64, 4) void win_attn(
    const u16*   __restrict__ qkv,   // [W*49, 768] bf16 chunk
    const float* __restrict__ comb,  // [64,8,64,64] fp32
    float* __restrict__ out,         // [W,49,256] fp32 chunk base
    int G4)                          // (windows per mask in chunk) / 4
{
    __shared__ u16 vT[32 * 72];      // V^T [d][tok], 4608 B

    const int lane = threadIdx.x, lrow = lane & 15, quad = lane >> 4;
    const int m = blockIdx.x;
    const int h = blockIdx.y / G4;
    const int grp = blockIdx.y % G4;
    const int qo = h * HDIM, ko = CDIM + h * HDIM, vo = 2 * CDIM + h * HDIM;

    const float* cb = comb + (((size_t)m * NHEAD + h) << 12);

    // zero vT pad cols (tokens 49..63) once; needed so 0-weight pad lanes
    // never multiply uninitialized (possibly NaN-pattern) LDS.
    for (int c = lane; c < 32 * 15; c += 64) vT[(c / 15) * 72 + NTOK + (c % 15)] = 0;

    for (int j = 0; j < 4; j++) {
        const int lw = m + 64 * (grp * 4 + j);
        const size_t rb = (size_t)lw * NTOK * 768;

        // ---- stage V transposed: [d][tok] ----
        for (int c = lane; c < NTOK * 8; c += 64) {
            int tok = c >> 3, d0 = (c & 7) * 4;
            uint2 v = *(const uint2*)&qkv[rb + (size_t)tok * 768 + vo + d0];
            vT[(d0 + 0) * 72 + tok] = (u16)(v.x & 0xffff);
            vT[(d0 + 1) * 72 + tok] = (u16)(v.x >> 16);
            vT[(d0 + 2) * 72 + tok] = (u16)(v.y & 0xffff);
            vT[(d0 + 3) * 72 + tok] = (u16)(v.y >> 16);
        }

        // ---- Q fragments (B operand), all 4 q-blocks ----
        bf16x8 bq[4];
#pragma unroll
        for (int tn = 0; tn < 4; tn++)
            bq[tn] = *(const bf16x8*)&qkv[rb + (size_t)(tn * 16 + lrow) * 768 + qo + quad * 8];

        float sum[4] = {0.f, 0.f, 0.f, 0.f};
        bf16x4 pk[4][4];   // [kt][tn]: P[q=tn*16+lrow][k=kt*16+quad*4+r], bf16

        // ---- QK^T (swapped) + softmax-exp, two k-halves of 32 ----
#pragma unroll
        for (int half = 0; half < 2; half++) {
            bf16x8 ak[2];
#pragma unroll
            for (int t = 0; t < 2; t++)
                ak[t] = *(const bf16x8*)&qkv[rb + (size_t)((half * 2 + t) * 16 + lrow) * 768 + ko + quad * 8];
            f32x4 s[2][4];
#pragma unroll
            for (int t = 0; t < 2; t++)
#pragma unroll
                for (int tn = 0; tn < 4; tn++) s[t][tn] = (f32x4){0.f, 0.f, 0.f, 0.f};
#pragma unroll
            for (int t = 0; t < 2; t++)
#pragma unroll
                for (int tn = 0; tn < 4; tn++)
                    s[t][tn] = __builtin_amdgcn_mfma_f32_16x16x32_bf16(ak[t], bq[tn], s[t][tn], 0, 0, 0);

            // scale + comb^T (streamed float4) + exp + partial per-q sums
#pragma unroll
            for (int t = 0; t < 2; t++) {
                const int kt = half * 2 + t;
#pragma unroll
                for (int tn = 0; tn < 4; tn++) {
                    float4 cv = *(const float4*)&cb[(size_t)(tn * 16 + lrow) * 64 + kt * 16 + quad * 4];
                    float e0 = __expf(s[t][tn][0] * SCALE_F + cv.x);
                    float e1 = __expf(s[t][tn][1] * SCALE_F + cv.y);
                    float e2 = __expf(s[t][tn][2] * SCALE_F + cv.z);
                    float e3 = __expf(s[t][tn][3] * SCALE_F + cv.w);
                    sum[tn] += (e0 + e1) + (e2 + e3);
                    bf16x4 p;
                    p[0] = (short)f2b(e0); p[1] = (short)f2b(e1);
                    p[2] = (short)f2b(e2); p[3] = (short)f2b(e3);
                    pk[kt][tn] = p;
                }
            }
        }

        // ---- per-q denominators: 2 shuffles (cross-quad) ----
        float inv[4];
#pragma unroll
        for (int tn = 0; tn < 4; tn++) {
            float sm = sum[tn];
            sm += __shfl_xor(sm, 16);
            sm += __shfl_xor(sm, 32);
            inv[tn] = 1.0f / sm;
        }

        // ---- PV: O^T[d][q] via mfma_16x16x16, A=V^T (LDS), B=pk (regs) ----
        f32x4 o[2][4];
#pragma unroll
        for (int td = 0; td < 2; td++)
#pragma unroll
            for (int tn = 0; tn < 4; tn++) o[td][tn] = (f32x4){0.f, 0.f, 0.f, 0.f};
#pragma unroll
        for (int kt = 0; kt < 4; kt++) {
            bf16x4 va[2];
#pragma unroll
            for (int td = 0; td < 2; td++)
                va[td] = *(const bf16x4*)&vT[(td * 16 + lrow) * 72 + kt * 16 + quad * 4];
#pragma unroll
            for (int td = 0; td < 2; td++)
#pragma unroll
                for (int tn = 0; tn < 4; tn++)
#if __has_builtin(__builtin_amdgcn_mfma_f32_16x16x16bf16_1k)
                    o[td][tn] = __builtin_amdgcn_mfma_f32_16x16x16bf16_1k(
                        va[td], pk[kt][tn], o[td][tn], 0, 0, 0);
#else
                    asm volatile("v_mfma_f32_16x16x16_bf16 %0, %1, %2, %0"
                                 : "+v"(o[td][tn]) : "v"(va[td]), "v"(pk[kt][tn]));
#endif
        }

        // ---- normalize + store ctx (fp32, float4/lane). O^T C-layout:
        //      col = q = tn*16+lrow, row = d = td*16+quad*4+r. ----
        float* ob = out + (size_t)lw * NTOK * CDIM + h * HDIM;
#pragma unroll
        for (int tn = 0; tn < 4; tn++) {
            int q = tn * 16 + lrow;
            if (q < NTOK) {
#pragma unroll
                for (int td = 0; td < 2; td++) {
                    float4 st;
                    st.x = o[td][tn][0] * inv[tn];
                    st.y = o[td][tn][1] * inv[tn];
                    st.z = o[td][tn][2] * inv[tn];
                    st.w = o[td][tn][3] * inv[tn];
                    *(float4*)&ob[(size_t)q * CDIM + td * 16 + quad * 4] = st;
                }
            }
        }
    }
}

// ---------------------------------------------------------------------------
extern "C" void kernel_launch(void* const* d_in, const int* in_sizes, int n_in,
                              void* d_out, int out_size, void* d_ws, size_t ws_size,
                              hipStream_t stream) {
    const float* hidden     = (const float*)d_in[0];   // [4096,49,256] fp32
    const float* mask       = (const float*)d_in[1];   // [64,49,49]    fp32
    const float* qkv_w      = (const float*)d_in[2];   // [768,256]     fp32
    const float* qkv_b      = (const float*)d_in[3];   // [768]         fp32
    const float* bias_table = (const float*)d_in[4];   // [169,8]       fp32
    const int*   rel_index  = (const int*)d_in[5];     // [49,49]       int32
    float* out = (float*)d_out;

    // ws: comb fp32 | W bf16 | hidden-chunk bf16 | qkv-chunk bf16 | 64K slack
    float* comb = (float*)d_ws;                              // 8,388,608 B
    u16* wbuf = (u16*)((char*)d_ws + 8388608);               //   393,216 B
    int W = 4096;   // windows per chunk; multiple of 256 keeps all grids exact
    while (W > 256 &&
           8388608ull + 393216ull + (size_t)W * NTOK * CDIM * 2
                      + (size_t)W * NTOK * 768 * 2 + 65536ull > ws_size)
        W >>= 1;
    const int nch = 4096 / W;
    const int G4 = W / 256;                     // (W/64)/4 window-groups
    u16* hbuf = wbuf + 196608;
    u16* qkvbuf = hbuf + (size_t)W * NTOK * CDIM;

    build_comb<<<dim3(8192), dim3(256), 0, stream>>>(bias_table, mask, rel_index, comb);
    conv_bf16<<<dim3(96), dim3(256), 0, stream>>>(qkv_w, wbuf, 196608 / 8);

    const int ce = W * NTOK * CDIM;             // chunk elems (multiple of 8)
    for (int c = 0; c < nch; c++) {
        conv_bf16<<<dim3((ce / 8 + 255) / 256), dim3(256), 0, stream>>>(
            hidden + (size_t)c * ce, hbuf, ce / 8);
        qkv_gemm<<<dim3(W * NTOK / 128, 6), dim3(256), 0, stream>>>(
            hbuf, wbuf, qkv_b, qkvbuf);
        win_attn<<<dim3(64, NHEAD * G4), dim3(64), 0, stream>>>(
            qkvbuf, comb, out + (size_t)c * ce, G4);
    }
}